// Round 5
// baseline (322.656 us; speedup 1.0000x reference)
//
#include <hip/hip_runtime.h>
#include <stdint.h>

typedef unsigned short u16;
using bf16x8 = __attribute__((ext_vector_type(8))) __bf16;
using f32x4  = __attribute__((ext_vector_type(4))) float;
using u16x8  = __attribute__((ext_vector_type(8))) unsigned short;
using u16x4  = __attribute__((ext_vector_type(4))) unsigned short;

#define NH   16
#define DHD  64
#define SEQ  2048
#define DD   1024

__device__ inline u16 bfbits(float f) {
    __bf16 h = (__bf16)f;                 // RTNE
    return __builtin_bit_cast(u16, h);
}

// async global->LDS, 16 B per lane (global_load_lds_dwordx4)
__device__ inline void gld16(const u16* g, u16* l) {
    __builtin_amdgcn_global_load_lds(
        (const __attribute__((address_space(1))) void*)g,
        (__attribute__((address_space(3))) void*)l,
        16, 0, 0);
}

// ---------------------------------------------------------------------------
// Transpose+convert 4 weight matrices (1024x1024): Wt_bf16[n][k] = W_f32[k][n]
// ---------------------------------------------------------------------------
__global__ __launch_bounds__(256) void transpose4(
    const float* __restrict__ s0, const float* __restrict__ s1,
    const float* __restrict__ s2, const float* __restrict__ s3,
    u16* __restrict__ d0, u16* __restrict__ d1,
    u16* __restrict__ d2, u16* __restrict__ d3)
{
    const float* src = s0; u16* dst = d0;
    if (blockIdx.z == 1) { src = s1; dst = d1; }
    else if (blockIdx.z == 2) { src = s2; dst = d2; }
    else if (blockIdx.z == 3) { src = s3; dst = d3; }

    __shared__ u16 tile[32][33];
    int tx = threadIdx.x, ty = threadIdx.y;            // block (32,8)
    int x = blockIdx.x * 32 + tx;
    int y0 = blockIdx.y * 32 + ty;
#pragma unroll
    for (int i = 0; i < 32; i += 8)
        tile[ty + i][tx] = bfbits(src[(size_t)(y0 + i) * DD + x]);
    __syncthreads();
    int x2 = blockIdx.y * 32 + tx;
    int y2 = blockIdx.x * 32 + ty;
#pragma unroll
    for (int i = 0; i < 32; i += 8)
        dst[(size_t)(y2 + i) * DD + x2] = tile[tx][ty + i];
}

// ---------------------------------------------------------------------------
// Streaming f32 -> bf16 convert (8 elements/thread). Serial path only.
// ---------------------------------------------------------------------------
__global__ __launch_bounds__(256) void cvt1(
    const float* __restrict__ src, u16* __restrict__ dst)
{
    size_t i = ((size_t)blockIdx.x * 256 + threadIdx.x) * 8;
    f32x4 a = *(const f32x4*)&src[i];
    f32x4 b = *(const f32x4*)&src[i + 4];
    u16x8 o;
#pragma unroll
    for (int j = 0; j < 4; ++j) { o[j] = bfbits(a[j]); o[j + 4] = bfbits(b[j]); }
    *(u16x8*)&dst[i] = o;
}

// ---------------------------------------------------------------------------
// GEMM: C(8192 x 1024) = A(8192 x 1024 bf16) @ B, B given transposed (Bt: N x K).
// 128x128 tile, BK=64 as two [128][32] sub-tiles, global_load_lds staging,
// 4 waves (2x2), wave 64x64. XCD-chunked bijective block swizzle.
// MODE 0: bf16 head-major (b,h,s,dh)
// MODE 2: bf16 transposed head-major [(bh*64+dh)*2048+s] (packed b64 stores)
// MODE 1: f32 row-major
// ---------------------------------------------------------------------------
template<int MODE>
__global__ __launch_bounds__(256) void gemm_bt16(
    const u16* __restrict__ A0,
    const u16* __restrict__ B0,
    void* __restrict__ C0)
{
    const int K = 1024;
    const u16* A = A0; const u16* Bt = B0; void* C = C0;

    __shared__ __align__(16) u16 As[2][128 * 32];
    __shared__ __align__(16) u16 Bs[2][128 * 32];

    const int t = threadIdx.x;
    const int wave = t >> 6, lane = t & 63;
    const int l15 = lane & 15, q4 = lane >> 4;
    const int wm = (wave >> 1) * 64, wn = (wave & 1) * 64;

    // XCD-chunked bijective swizzle (nwg % 8 == 0)
    const int gx = gridDim.x;
    const int nwg = gx * gridDim.y;
    int flat = blockIdx.y * gx + blockIdx.x;
    flat = (flat & 7) * (nwg >> 3) + (flat >> 3);
    const int m0 = (flat / gx) * 128, n0 = (flat % gx) * 128;

    const int ar = t >> 2;             // row within 64-row group
    const int ac = (t & 3) * 8;        // col (u16 units)

    const u16* gA = &A [(size_t)(m0 + ar) * K + ac];
    const u16* gB = &Bt[(size_t)(n0 + ar) * K + ac];
    u16* lA0 = &As[0][t * 8];          // byte offset = t*16 (lane-contiguous)
    u16* lA1 = &As[1][t * 8];
    u16* lB0 = &Bs[0][t * 8];
    u16* lB1 = &Bs[1][t * 8];

    f32x4 acc[4][4] = {};

    for (int k0 = 0; k0 < K; k0 += 64) {
        __syncthreads();
        gld16(gA + k0,                   lA0);
        gld16(gA + (size_t)64 * K + k0,  lA0 + 64 * 32);
        gld16(gA + k0 + 32,              lA1);
        gld16(gA + (size_t)64 * K + k0 + 32, lA1 + 64 * 32);
        gld16(gB + k0,                   lB0);
        gld16(gB + (size_t)64 * K + k0,  lB0 + 64 * 32);
        gld16(gB + k0 + 32,              lB1);
        gld16(gB + (size_t)64 * K + k0 + 32, lB1 + 64 * 32);
        __syncthreads();   // drains vmcnt -> LDS valid

#pragma unroll
        for (int hf = 0; hf < 2; ++hf) {
            bf16x8 af[4], bfr[4];
#pragma unroll
            for (int i = 0; i < 4; ++i) {
                af[i]  = *(const bf16x8*)&As[hf][(wm + i * 16 + l15) * 32 + q4 * 8];
                bfr[i] = *(const bf16x8*)&Bs[hf][(wn + i * 16 + l15) * 32 + q4 * 8];
            }
#pragma unroll
            for (int i = 0; i < 4; ++i)
#pragma unroll
                for (int j = 0; j < 4; ++j)
                    acc[i][j] = __builtin_amdgcn_mfma_f32_16x16x32_bf16(af[i], bfr[j], acc[i][j], 0, 0, 0);
        }
    }

    // epilogue: D layout col=lane&15, row=(lane>>4)*4+reg
#pragma unroll
    for (int i = 0; i < 4; ++i) {
        int row_l = wm + i * 16 + q4 * 4;
#pragma unroll
        for (int j = 0; j < 4; ++j) {
            int col = n0 + wn + j * 16 + l15;
            if (MODE == 1) {
#pragma unroll
                for (int r = 0; r < 4; ++r) {
                    int row = m0 + row_l + r;
                    ((float*)C)[(size_t)row * DD + col] = acc[i][j][r];
                }
            } else if (MODE == 2) {
                int row = m0 + row_l;
                int b = row >> 11, s = row & (SEQ - 1);
                int h = col >> 6, dh = col & (DHD - 1);
                u16x4 pk;
#pragma unroll
                for (int r = 0; r < 4; ++r) pk[r] = bfbits(acc[i][j][r]);
                *(u16x4*)&((u16*)C)[(((size_t)(b * NH + h) * DHD + dh) << 11) | s] = pk;
            } else {
#pragma unroll
                for (int r = 0; r < 4; ++r) {
                    int row = m0 + row_l + r;
                    int b = row >> 11, s = row & (SEQ - 1);
                    int h = col >> 6, dh = col & (DHD - 1);
                    ((u16*)C)[(((size_t)(b * NH + h) * SEQ + s) << 6) | dh] = bfbits(acc[i][j][r]);
                }
            }
        }
    }
}

// ---------------------------------------------------------------------------
// Fused QKV projection GEMM with in-kernel f32->bf16 A conversion (kills cvt3).
// A is f32 (Q/K/V raw inputs); B bf16 transposed weights; C bf16 head layouts.
// A staging: reg-prefetch one K-step AHEAD (8x dwordx4 in flight across both
// barriers via counted vmcnt), cvt in-reg (RTNE == cvt3 exactly), ds_write_b128.
// B staging: global_load_lds DMA as before. Barrier discipline:
//   top:  lgkmcnt(0); s_barrier            (prev compute done, LDS writable)
//         vmcnt(0)                          (A(k0) regs landed)
//         cvt + ds_write A ; gld16 B x4 ; issue A(k0+64) loads
//         vmcnt(8) lgkmcnt(0); s_barrier   (B DMA done; A prefetch IN FLIGHT)
//   compute 32 MFMA
// blockIdx.z selects Q/K/V; z<2 stores MODE0-style, z==2 MODE2-style.
// ---------------------------------------------------------------------------
__global__ __launch_bounds__(256) void gemm_qkv(
    const float* __restrict__ A0, const float* __restrict__ A1,
    const float* __restrict__ A2,
    const u16* __restrict__ B0, const u16* __restrict__ B1,
    const u16* __restrict__ B2,
    u16* __restrict__ C0, u16* __restrict__ C1, u16* __restrict__ C2)
{
    const int K = 1024;
    const float* A = A0; const u16* Bt = B0; u16* C = C0;
    if (blockIdx.z == 1) { A = A1; Bt = B1; C = C1; }
    else if (blockIdx.z == 2) { A = A2; Bt = B2; C = C2; }

    __shared__ __align__(16) u16 As[2][128 * 32];
    __shared__ __align__(16) u16 Bs[2][128 * 32];

    const int t = threadIdx.x;
    const int wave = t >> 6, lane = t & 63;
    const int l15 = lane & 15, q4 = lane >> 4;
    const int wm = (wave >> 1) * 64, wn = (wave & 1) * 64;

    // XCD-chunked bijective swizzle (nwg = 512 per z, 512 % 8 == 0)
    const int gx = gridDim.x;
    const int nwg = gx * gridDim.y;
    int flat = blockIdx.y * gx + blockIdx.x;
    flat = (flat & 7) * (nwg >> 3) + (flat >> 3);
    const int m0 = (flat / gx) * 128, n0 = (flat % gx) * 128;

    const int ar = t >> 2;             // row within 64-row group
    const int ac = (t & 3) * 8;        // col (elements)

    const float* gAf = &A [(size_t)(m0 + ar) * K + ac];
    const u16*   gB  = &Bt[(size_t)(n0 + ar) * K + ac];
    u16* lB0 = &Bs[0][t * 8];
    u16* lB1 = &Bs[1][t * 8];

    // prologue: issue A(k0=0) loads into regs
    f32x4 areg[8];
#pragma unroll
    for (int p = 0; p < 4; ++p) {   // p = (hf<<1 | rg) with hf=p>>1, rg=p&1
        const float* src = gAf + (p >> 1) * 32 + (size_t)(p & 1) * 64 * K;
        areg[2 * p]     = *(const f32x4*)src;
        areg[2 * p + 1] = *(const f32x4*)(src + 4);
    }

    f32x4 acc[4][4] = {};

    for (int k0 = 0; k0 < K; k0 += 64) {
        asm volatile("s_waitcnt lgkmcnt(0)" ::: "memory");
        __builtin_amdgcn_s_barrier();                       // LDS writable
        asm volatile("s_waitcnt vmcnt(0)" ::: "memory");    // A(k0) regs ready
        __builtin_amdgcn_sched_barrier(0);

        // cvt + ds_write A (same LDS layout the DMA produced before)
#pragma unroll
        for (int p = 0; p < 4; ++p) {
            u16x8 w;
#pragma unroll
            for (int j = 0; j < 4; ++j) {
                w[j]     = bfbits(areg[2 * p][j]);
                w[j + 4] = bfbits(areg[2 * p + 1][j]);
            }
            *(u16x8*)&As[p >> 1][t * 8 + (p & 1) * 2048] = w;
        }
        // B DMA (4 vmem, oldest in FIFO)
        gld16(gB + k0,                       lB0);
        gld16(gB + (size_t)64 * K + k0,      lB0 + 2048);
        gld16(gB + k0 + 32,                  lB1);
        gld16(gB + (size_t)64 * K + k0 + 32, lB1 + 2048);
        __builtin_amdgcn_sched_barrier(0);

        // prefetch A(k0+64) -> regs (8 vmem, behind the B DMAs)
        const bool pre = (k0 + 64 < K);
        if (pre) {
#pragma unroll
            for (int p = 0; p < 4; ++p) {
                const float* src = gAf + (k0 + 64) + (p >> 1) * 32 + (size_t)(p & 1) * 64 * K;
                areg[2 * p]     = *(const f32x4*)src;
                areg[2 * p + 1] = *(const f32x4*)(src + 4);
            }
        }
        __builtin_amdgcn_sched_barrier(0);
        // drain B DMA (4 oldest) + A ds_writes; keep 8 A-prefetch loads alive
        if (pre) asm volatile("s_waitcnt vmcnt(8) lgkmcnt(0)" ::: "memory");
        else     asm volatile("s_waitcnt vmcnt(0) lgkmcnt(0)" ::: "memory");
        __builtin_amdgcn_sched_barrier(0);
        __builtin_amdgcn_s_barrier();                       // LDS valid

#pragma unroll
        for (int hf = 0; hf < 2; ++hf) {
            bf16x8 af[4], bfr[4];
#pragma unroll
            for (int i = 0; i < 4; ++i) {
                af[i]  = *(const bf16x8*)&As[hf][(wm + i * 16 + l15) * 32 + q4 * 8];
                bfr[i] = *(const bf16x8*)&Bs[hf][(wn + i * 16 + l15) * 32 + q4 * 8];
            }
#pragma unroll
            for (int i = 0; i < 4; ++i)
#pragma unroll
                for (int j = 0; j < 4; ++j)
                    acc[i][j] = __builtin_amdgcn_mfma_f32_16x16x32_bf16(af[i], bfr[j], acc[i][j], 0, 0, 0);
        }
    }

    const bool vt_store = (blockIdx.z == 2);

    // epilogue: D layout col=lane&15, row=(lane>>4)*4+reg
#pragma unroll
    for (int i = 0; i < 4; ++i) {
        int row_l = wm + i * 16 + q4 * 4;
#pragma unroll
        for (int j = 0; j < 4; ++j) {
            int col = n0 + wn + j * 16 + l15;
            if (vt_store) {
                int row = m0 + row_l;
                int b = row >> 11, s = row & (SEQ - 1);
                int h = col >> 6, dh = col & (DHD - 1);
                u16x4 pk;
#pragma unroll
                for (int r = 0; r < 4; ++r) pk[r] = bfbits(acc[i][j][r]);
                *(u16x4*)&C[(((size_t)(b * NH + h) * DHD + dh) << 11) | s] = pk;
            } else {
#pragma unroll
                for (int r = 0; r < 4; ++r) {
                    int row = m0 + row_l + r;
                    int b = row >> 11, s = row & (SEQ - 1);
                    int h = col >> 6, dh = col & (DHD - 1);
                    C[(((size_t)(b * NH + h) * SEQ + s) << 6) | dh] = bfbits(acc[i][j][r]);
                }
            }
        }
    }
}

// ---------------------------------------------------------------------------
// Flash attention: one block per (b,h, 128-row q-tile). 4 waves, 32 q-rows each.
// q/k head-major (b,h,s,dh); v transposed head-major (b,h,dh,s). All bf16.
// Fixed-max softmax: p = exp2(s*c2 - M2) via raw v_exp_f32; masked -> 0 exact.
// K-tiles fully beyond valid are SKIPPED (exact). valid==0 -> uniform weights.
// Swapped QK^T (mfma(kf,qf)): packed u16x4 P stores; no shuffles anywhere.
// Staging: K double-buffered + V SINGLE-buffered via global_load_lds with XOR
// bank-swizzle (pre-swizzled global source + XOR'd read). Per tile:
//   syncthreads -> issue V[t] DMA, issue K[t+1] DMA -> QK^T -> softmax -> Ps
//   -> s_waitcnt vmcnt(2) + s_barrier (V[t] drained, K[t+1] stays in flight)
//   -> PV. LDS = 40960 B -> 4 blocks/CU.
// ---------------------------------------------------------------------------
__global__ __launch_bounds__(256, 4) void attn(
    const u16* __restrict__ q_ws, const u16* __restrict__ k_ws,
    const u16* __restrict__ vT_ws, const int* __restrict__ valid_lens,
    u16* __restrict__ o_ws)
{
    const int bh = blockIdx.y;           // 0..63
    const int b = bh >> 4, h = bh & 15;
    const int qt = blockIdx.x;           // 0..15
    const int valid = valid_lens[b];
    const bool valid0 = (valid == 0);
    const int valid_eff = valid0 ? SEQ : valid;
    const int kt_n = (valid_eff + 63) >> 6;
    const float c2 = valid0 ? 0.f : 0.18033688011112042f;   // 0.125*log2(e)
    const float M2 = 17.312340490667562f;                   // 12*log2(e)

    __shared__ __align__(16) u16 Kbuf[2][64 * 64];   // 16 KB (dbuf)
    __shared__ __align__(16) u16 Vbuf[64 * 64];      //  8 KB (single)
    __shared__ __align__(16) u16 Ps[4][32][64];      // 16 KB, XOR-swizzled cols

    const int t = threadIdx.x;
    const int wave = t >> 6, lane = t & 63;
    const int l15 = lane & 15, q4 = lane >> 4;

    const size_t base  = (size_t)bh * SEQ * DHD;   // q/k head-major
    const size_t vbase = (size_t)bh * DHD * SEQ;   // vT

    const int q0 = qt * 128 + wave * 32;

    // staging lane constants: wave stages rows [wave*16, wave*16+16)
    const int sr0 = wave * 16 + (lane >> 3);            // rows sr0 and sr0+8
    const int cg  = ((lane & 7) ^ (sr0 & 7)) * 8;       // swizzled src col (u16)
    const u16* gK = &k_ws [base  + (size_t)sr0 * DHD + cg];
    const u16* gV = &vT_ws[vbase + (size_t)sr0 * SEQ + cg];
    const int ldst = sr0 * 64 + (lane & 7) * 8;         // linear LDS dest (u16)

    u16x8 ou;
#pragma unroll
    for (int j = 0; j < 8; ++j) ou[j] = 0x3F80;
    const bf16x8 ones = __builtin_bit_cast(bf16x8, ou);

    bf16x8 qf[2][2];
#pragma unroll
    for (int mi = 0; mi < 2; ++mi)
#pragma unroll
        for (int c = 0; c < 2; ++c)
            qf[mi][c] = *(const bf16x8*)&q_ws[base + (size_t)(q0 + mi * 16 + l15) * DHD + c * 32 + q4 * 8];

    f32x4 o4[2][4] = {};
    f32x4 l_acc[2] = {};

    const int swz  = (l15 & 7) * 8;      // read-side XOR for K/V (u16 units)

    // prologue: stage K tile 0 into buffer 0
    gld16(gK,       &Kbuf[0][ldst]);
    gld16(gK + 512, &Kbuf[0][ldst + 512]);

    int cur = 0;
    for (int kt = 0; kt < kt_n; ++kt) {
        __syncthreads();   // implicit vmcnt(0): own K[kt] DMA done; all waves
                           // arrived => K[kt] fully in LDS, V[kt-1] consumed.
        // issue V[kt] into the single V buffer (latency hides under QK+softmax)
        {
            const u16* vv = gV + (size_t)kt * 64;
            gld16(vv,                   &Vbuf[ldst]);
            gld16(vv + (size_t)8 * SEQ, &Vbuf[ldst + 512]);
        }
        const bool pre = (kt + 1 < kt_n);
        if (pre) {
            const u16* kk = gK + (size_t)(kt + 1) * 64 * DHD;
            int bf = cur ^ 1;
            gld16(kk,       &Kbuf[bf][ldst]);
            gld16(kk + 512, &Kbuf[bf][ldst + 512]);
        }

        const u16* KK = Kbuf[cur];

        // swapped QK^T: s4[mi][ni][r] = S[q = mi*16+l15][key = ni*16+q4*4+r]
        f32x4 s4[2][4] = {};
#pragma unroll
        for (int c = 0; c < 2; ++c)
#pragma unroll
            for (int ni = 0; ni < 4; ++ni) {
                bf16x8 kf = *(const bf16x8*)&KK[(ni * 16 + l15) * 64 + ((c * 32 + q4 * 8) ^ swz)];
#pragma unroll
                for (int mi = 0; mi < 2; ++mi)
                    s4[mi][ni] = __builtin_amdgcn_mfma_f32_16x16x32_bf16(kf, qf[mi][c], s4[mi][ni], 0, 0, 0);
            }

        // softmax -> Ps (col XOR-swizzled by (qrow&7)*8; b64 stores stay in-group)
        const bool tile_full = valid0 || (kt * 64 + 64 <= valid_eff);
        if (tile_full) {
#pragma unroll
            for (int mi = 0; mi < 2; ++mi) {
                int qrow = mi * 16 + l15;
                int psw  = (l15 & 7) * 8;
#pragma unroll
                for (int ni = 0; ni < 4; ++ni) {
                    u16x4 pk;
#pragma unroll
                    for (int r = 0; r < 4; ++r) {
                        float p = __builtin_amdgcn_exp2f(__builtin_fmaf(s4[mi][ni][r], c2, -M2));
                        pk[r] = bfbits(p);
                    }
                    *(u16x4*)&Ps[wave][qrow][(ni * 16 + q4 * 4) ^ psw] = pk;
                }
            }
        } else {
#pragma unroll
            for (int mi = 0; mi < 2; ++mi) {
                int qrow = mi * 16 + l15;
                int psw  = (l15 & 7) * 8;
#pragma unroll
                for (int ni = 0; ni < 4; ++ni) {
                    u16x4 pk;
#pragma unroll
                    for (int r = 0; r < 4; ++r) {
                        bool ok = (kt * 64 + ni * 16 + q4 * 4 + r) < valid_eff;
                        float arg = ok ? __builtin_fmaf(s4[mi][ni][r], c2, -M2) : -1e30f;
                        pk[r] = bfbits(__builtin_amdgcn_exp2f(arg));
                    }
                    *(u16x4*)&Ps[wave][qrow][(ni * 16 + q4 * 4) ^ psw] = pk;
                }
            }
        }

        // mid-tile barrier: drain V[kt] (2 oldest loads) but keep K[kt+1] in
        // flight across the barrier (counted vmcnt, T4).
        if (pre) asm volatile("s_waitcnt vmcnt(2)\n\ts_barrier" ::: "memory");
        else     asm volatile("s_waitcnt vmcnt(0)\n\ts_barrier" ::: "memory");

        // O += P @ V ;  l += P @ 1
#pragma unroll
        for (int c = 0; c < 2; ++c) {
            bf16x8 pf[2];
#pragma unroll
            for (int mi = 0; mi < 2; ++mi) {
                pf[mi] = *(const bf16x8*)&Ps[wave][mi * 16 + l15][(c * 32 + q4 * 8) ^ ((l15 & 7) * 8)];
                l_acc[mi] = __builtin_amdgcn_mfma_f32_16x16x32_bf16(pf[mi], ones, l_acc[mi], 0, 0, 0);
            }
#pragma unroll
            for (int dt = 0; dt < 4; ++dt) {
                bf16x8 vf = *(const bf16x8*)&Vbuf[(dt * 16 + l15) * 64 + ((c * 32 + q4 * 8) ^ swz)];
#pragma unroll
                for (int mi = 0; mi < 2; ++mi)
                    o4[mi][dt] = __builtin_amdgcn_mfma_f32_16x16x32_bf16(pf[mi], vf, o4[mi][dt], 0, 0, 0);
            }
        }
        cur ^= 1;
    }

    // epilogue: concat heads -> o_ws[(b*S+q)*D + h*64+dh]  (bf16)
#pragma unroll
    for (int mi = 0; mi < 2; ++mi) {
        float inv[4];
#pragma unroll
        for (int r = 0; r < 4; ++r) inv[r] = 1.0f / l_acc[mi][r];
        int qrow = q0 + mi * 16 + q4 * 4;
#pragma unroll
        for (int dt = 0; dt < 4; ++dt) {
            int dh = dt * 16 + l15;
#pragma unroll
            for (int r = 0; r < 4; ++r) {
                float v = o4[mi][dt][r] * inv[r];
                o_ws[((size_t)(b * SEQ + qrow + r) << 10) | (h * DHD + dh)] = bfbits(v);
            }
        }
    }
}

// ---------------------------------------------------------------------------
extern "C" void kernel_launch(void* const* d_in, const int* in_sizes, int n_in,
                              void* d_out, int out_size, void* d_ws, size_t ws_size,
                              hipStream_t stream)
{
    (void)in_sizes; (void)n_in; (void)out_size;
    const float* Q  = (const float*)d_in[0];
    const float* Kb = (const float*)d_in[1];
    const float* V  = (const float*)d_in[2];
    const int*   vl = (const int*)d_in[3];
    const float* Wq = (const float*)d_in[4];
    const float* Wk = (const float*)d_in[5];
    const float* Wv = (const float*)d_in[6];
    const float* Wo = (const float*)d_in[7];
    float* out = (float*)d_out;

    char* ws = (char*)d_ws;
    u16* WqT   = (u16*)(ws + (size_t)0);
    u16* WkT   = (u16*)(ws + ((size_t)2 << 20));
    u16* WvT   = (u16*)(ws + ((size_t)4 << 20));
    u16* WoT   = (u16*)(ws + ((size_t)6 << 20));
    u16* q_ws  = (u16*)(ws + ((size_t)8 << 20));
    u16* k_ws  = (u16*)(ws + ((size_t)24 << 20));
    u16* vT_ws = (u16*)(ws + ((size_t)40 << 20));
    u16* o_ws  = (u16*)(ws + ((size_t)56 << 20));   // attn out / serial A-scratch

    transpose4<<<dim3(32, 32, 4), dim3(32, 8), 0, stream>>>(
        Wq, Wk, Wv, Wo, WqT, WkT, WvT, WoT);

    const bool fused = ws_size >= ((size_t)120 << 20);
    if (fused) {
        // QKV projections with in-kernel f32->bf16 A conversion (no cvt pass)
        gemm_qkv<<<dim3(8, 64, 3), 256, 0, stream>>>(
            Q, Kb, V, WqT, WkT, WvT, q_ws, k_ws, vT_ws);
    } else {
        cvt1<<<4096, 256, 0, stream>>>(Q, o_ws);
        gemm_bt16<0><<<dim3(8, 64), 256, 0, stream>>>(o_ws, WqT, q_ws);
        cvt1<<<4096, 256, 0, stream>>>(Kb, o_ws);
        gemm_bt16<0><<<dim3(8, 64), 256, 0, stream>>>(o_ws, WkT, k_ws);
        cvt1<<<4096, 256, 0, stream>>>(V, o_ws);
        gemm_bt16<2><<<dim3(8, 64), 256, 0, stream>>>(o_ws, WvT, vT_ws);
    }

    attn<<<dim3(16, 64), 256, 0, stream>>>(q_ws, k_ws, vT_ws, vl, o_ws);

    gemm_bt16<1><<<dim3(8, 64), 256, 0, stream>>>(o_ws, WoT, out);
}

// Round 6
// 289.837 us; speedup vs baseline: 1.1132x; 1.1132x over previous
//
#include <hip/hip_runtime.h>
#include <stdint.h>

typedef unsigned short u16;
using bf16x8 = __attribute__((ext_vector_type(8))) __bf16;
using f32x4  = __attribute__((ext_vector_type(4))) float;
using u16x8  = __attribute__((ext_vector_type(8))) unsigned short;
using u16x4  = __attribute__((ext_vector_type(4))) unsigned short;

#define NH   16
#define DHD  64
#define SEQ  2048
#define DD   1024

__device__ inline u16 bfbits(float f) {
    __bf16 h = (__bf16)f;                 // RTNE
    return __builtin_bit_cast(u16, h);
}

// async global->LDS, 16 B per lane (global_load_lds_dwordx4)
__device__ inline void gld16(const u16* g, u16* l) {
    __builtin_amdgcn_global_load_lds(
        (const __attribute__((address_space(1))) void*)g,
        (__attribute__((address_space(3))) void*)l,
        16, 0, 0);
}

// ---------------------------------------------------------------------------
// Transpose+convert 4 weight matrices (1024x1024): Wt_bf16[n][k] = W_f32[k][n]
// ---------------------------------------------------------------------------
__global__ __launch_bounds__(256) void transpose4(
    const float* __restrict__ s0, const float* __restrict__ s1,
    const float* __restrict__ s2, const float* __restrict__ s3,
    u16* __restrict__ d0, u16* __restrict__ d1,
    u16* __restrict__ d2, u16* __restrict__ d3)
{
    const float* src = s0; u16* dst = d0;
    if (blockIdx.z == 1) { src = s1; dst = d1; }
    else if (blockIdx.z == 2) { src = s2; dst = d2; }
    else if (blockIdx.z == 3) { src = s3; dst = d3; }

    __shared__ u16 tile[32][33];
    int tx = threadIdx.x, ty = threadIdx.y;            // block (32,8)
    int x = blockIdx.x * 32 + tx;
    int y0 = blockIdx.y * 32 + ty;
#pragma unroll
    for (int i = 0; i < 32; i += 8)
        tile[ty + i][tx] = bfbits(src[(size_t)(y0 + i) * DD + x]);
    __syncthreads();
    int x2 = blockIdx.y * 32 + tx;
    int y2 = blockIdx.x * 32 + ty;
#pragma unroll
    for (int i = 0; i < 32; i += 8)
        dst[(size_t)(y2 + i) * DD + x2] = tile[tx][ty + i];
}

// ---------------------------------------------------------------------------
// Streaming f32 -> bf16 convert (8 elements/thread). cvt3: three matrices.
// For z>=1 (K,V inputs): rows entirely beyond the per-batch validity limit
// (rounded up to the GEMM's 128-row tile) are never read by the projection
// GEMM (those tiles early-exit) -> skip the conversion (block-uniform).
// ---------------------------------------------------------------------------
__global__ __launch_bounds__(256) void cvt3(
    const float* __restrict__ s0, const float* __restrict__ s1,
    const float* __restrict__ s2,
    u16* __restrict__ d0, u16* __restrict__ d1, u16* __restrict__ d2,
    const int* __restrict__ vl)
{
    const float* src = s0; u16* dst = d0;
    if (blockIdx.z == 1) { src = s1; dst = d1; }
    else if (blockIdx.z == 2) { src = s2; dst = d2; }

    if (blockIdx.z != 0) {
        int r = blockIdx.x * 2;            // first of 2 rows this block covers
        int v = vl[r >> 11];
        int ve = (v == 0) ? SEQ : v;
        int lim = ((ve + 127) >> 7) << 7;  // GEMM read extent (tile-rounded)
        if ((r & (SEQ - 1)) >= lim) return;
    }

    size_t i = ((size_t)blockIdx.x * 256 + threadIdx.x) * 8;
    f32x4 a = *(const f32x4*)&src[i];
    f32x4 b = *(const f32x4*)&src[i + 4];
    u16x8 o;
#pragma unroll
    for (int j = 0; j < 4; ++j) { o[j] = bfbits(a[j]); o[j + 4] = bfbits(b[j]); }
    *(u16x8*)&dst[i] = o;
}

__global__ __launch_bounds__(256) void cvt1(
    const float* __restrict__ src, u16* __restrict__ dst)
{
    size_t i = ((size_t)blockIdx.x * 256 + threadIdx.x) * 8;
    f32x4 a = *(const f32x4*)&src[i];
    f32x4 b = *(const f32x4*)&src[i + 4];
    u16x8 o;
#pragma unroll
    for (int j = 0; j < 4; ++j) { o[j] = bfbits(a[j]); o[j + 4] = bfbits(b[j]); }
    *(u16x8*)&dst[i] = o;
}

// ---------------------------------------------------------------------------
// GEMM: C(8192 x 1024) = A(8192 x 1024 bf16) @ B, B given transposed (Bt: N x K).
// 128x128 tile, BK=64 as two [128][32] sub-tiles (conflict-free b128 reads,
// half the barriers), global_load_lds staging, 4 waves (2x2), wave 64x64.
// XCD-chunked bijective block swizzle (nwg%8==0; z offsets are mult of 512).
// MODE 0: bf16 head-major (b,h,s,dh)
// MODE 2: bf16 transposed head-major [(bh*64+dh)*2048+s] (packed b64 stores)
// MODE 1: f32 row-major
// MODE 3: fused QKV via blockIdx.z: z<2 -> MODE0-style, z==2 -> MODE2-style.
//   Validity skip (MODE3, z>=1): K/V projection tiles whose 128 rows start at
//   or beyond valid_eff[batch] are never read by attn (it iterates K-tiles
//   only to ceil(valid_eff/64)*64 <= next 128-boundary) -> early-exit.
//   Masked-but-read rows of attn's last partial tile always lie in a
//   NON-skipped tile, so they hold finite projected data (no 0*NaN).
// ---------------------------------------------------------------------------
template<int MODE>
__global__ __launch_bounds__(256) void gemm_bt16(
    const u16* __restrict__ A0, const u16* __restrict__ A1, const u16* __restrict__ A2,
    const u16* __restrict__ B0, const u16* __restrict__ B1, const u16* __restrict__ B2,
    void* __restrict__ C0, void* __restrict__ C1, void* __restrict__ C2,
    const int* __restrict__ vl)
{
    const int K = 1024;
    const u16* A = A0; const u16* Bt = B0; void* C = C0;
    if (MODE == 3) {
        if (blockIdx.z == 1) { A = A1; Bt = B1; C = C1; }
        else if (blockIdx.z == 2) { A = A2; Bt = B2; C = C2; }
    }

    __shared__ __align__(16) u16 As[2][128 * 32];
    __shared__ __align__(16) u16 Bs[2][128 * 32];

    const int t = threadIdx.x;
    const int wave = t >> 6, lane = t & 63;
    const int l15 = lane & 15, q4 = lane >> 4;
    const int wm = (wave >> 1) * 64, wn = (wave & 1) * 64;

    // XCD-chunked bijective swizzle (nwg % 8 == 0)
    const int gx = gridDim.x;
    const int nwg = gx * gridDim.y;
    int flat = blockIdx.y * gx + blockIdx.x;
    flat = (flat & 7) * (nwg >> 3) + (flat >> 3);
    const int m0 = (flat / gx) * 128, n0 = (flat % gx) * 128;

    if (MODE == 3 && blockIdx.z != 0) {
        int v = vl[m0 >> 11];
        int ve = (v == 0) ? SEQ : v;
        if ((m0 & (SEQ - 1)) >= ve) return;   // block-uniform, pre-barrier
    }

    const int ar = t >> 2;             // row within 64-row group
    const int ac = (t & 3) * 8;        // col (u16 units)

    const u16* gA = &A [(size_t)(m0 + ar) * K + ac];
    const u16* gB = &Bt[(size_t)(n0 + ar) * K + ac];
    u16* lA0 = &As[0][t * 8];          // byte offset = t*16 (lane-contiguous)
    u16* lA1 = &As[1][t * 8];
    u16* lB0 = &Bs[0][t * 8];
    u16* lB1 = &Bs[1][t * 8];

    f32x4 acc[4][4] = {};

    for (int k0 = 0; k0 < K; k0 += 64) {
        __syncthreads();
        gld16(gA + k0,                   lA0);
        gld16(gA + (size_t)64 * K + k0,  lA0 + 64 * 32);
        gld16(gA + k0 + 32,              lA1);
        gld16(gA + (size_t)64 * K + k0 + 32, lA1 + 64 * 32);
        gld16(gB + k0,                   lB0);
        gld16(gB + (size_t)64 * K + k0,  lB0 + 64 * 32);
        gld16(gB + k0 + 32,              lB1);
        gld16(gB + (size_t)64 * K + k0 + 32, lB1 + 64 * 32);
        __syncthreads();   // drains vmcnt -> LDS valid

#pragma unroll
        for (int hf = 0; hf < 2; ++hf) {
            bf16x8 af[4], bfr[4];
#pragma unroll
            for (int i = 0; i < 4; ++i) {
                af[i]  = *(const bf16x8*)&As[hf][(wm + i * 16 + l15) * 32 + q4 * 8];
                bfr[i] = *(const bf16x8*)&Bs[hf][(wn + i * 16 + l15) * 32 + q4 * 8];
            }
#pragma unroll
            for (int i = 0; i < 4; ++i)
#pragma unroll
                for (int j = 0; j < 4; ++j)
                    acc[i][j] = __builtin_amdgcn_mfma_f32_16x16x32_bf16(af[i], bfr[j], acc[i][j], 0, 0, 0);
        }
    }

    const bool vt_store = (MODE == 2) || (MODE == 3 && blockIdx.z == 2);

    // epilogue: D layout col=lane&15, row=(lane>>4)*4+reg
#pragma unroll
    for (int i = 0; i < 4; ++i) {
        int row_l = wm + i * 16 + q4 * 4;
#pragma unroll
        for (int j = 0; j < 4; ++j) {
            int col = n0 + wn + j * 16 + l15;
            if (MODE == 1) {
#pragma unroll
                for (int r = 0; r < 4; ++r) {
                    int row = m0 + row_l + r;
                    ((float*)C)[(size_t)row * DD + col] = acc[i][j][r];
                }
            } else if (vt_store) {
                int row = m0 + row_l;
                int b = row >> 11, s = row & (SEQ - 1);
                int h = col >> 6, dh = col & (DHD - 1);
                u16x4 pk;
#pragma unroll
                for (int r = 0; r < 4; ++r) pk[r] = bfbits(acc[i][j][r]);
                *(u16x4*)&((u16*)C)[(((size_t)(b * NH + h) * DHD + dh) << 11) | s] = pk;
            } else {
#pragma unroll
                for (int r = 0; r < 4; ++r) {
                    int row = m0 + row_l + r;
                    int b = row >> 11, s = row & (SEQ - 1);
                    int h = col >> 6, dh = col & (DHD - 1);
                    ((u16*)C)[(((size_t)(b * NH + h) * SEQ + s) << 6) | dh] = bfbits(acc[i][j][r]);
                }
            }
        }
    }
}

// ---------------------------------------------------------------------------
// Flash attention: one block per (b,h, 128-row q-tile). 4 waves, 32 q-rows each.
// q/k head-major (b,h,s,dh); v transposed head-major (b,h,dh,s). All bf16.
// Fixed-max softmax: p = exp2(s*c2 - M2) via raw v_exp_f32; masked -> 0 exact.
// K-tiles fully beyond valid are SKIPPED (exact). valid==0 -> uniform weights.
// Swapped QK^T (mfma(kf,qf)): packed u16x4 P stores; no shuffles anywhere.
// Staging: K double-buffered + V SINGLE-buffered via global_load_lds with XOR
// bank-swizzle (pre-swizzled global source + XOR'd read). Per tile:
//   syncthreads -> issue V[t] DMA, issue K[t+1] DMA -> QK^T -> softmax -> Ps
//   -> s_waitcnt vmcnt(2) + s_barrier (V[t] drained, K[t+1] stays in flight)
//   -> PV. LDS = 40960 B -> 4 blocks/CU.
// ---------------------------------------------------------------------------
__global__ __launch_bounds__(256, 4) void attn(
    const u16* __restrict__ q_ws, const u16* __restrict__ k_ws,
    const u16* __restrict__ vT_ws, const int* __restrict__ valid_lens,
    u16* __restrict__ o_ws)
{
    const int bh = blockIdx.y;           // 0..63
    const int b = bh >> 4, h = bh & 15;
    const int qt = blockIdx.x;           // 0..15
    const int valid = valid_lens[b];
    const bool valid0 = (valid == 0);
    const int valid_eff = valid0 ? SEQ : valid;
    const int kt_n = (valid_eff + 63) >> 6;
    const float c2 = valid0 ? 0.f : 0.18033688011112042f;   // 0.125*log2(e)
    const float M2 = 17.312340490667562f;                   // 12*log2(e)

    __shared__ __align__(16) u16 Kbuf[2][64 * 64];   // 16 KB (dbuf)
    __shared__ __align__(16) u16 Vbuf[64 * 64];      //  8 KB (single)
    __shared__ __align__(16) u16 Ps[4][32][64];      // 16 KB, XOR-swizzled cols

    const int t = threadIdx.x;
    const int wave = t >> 6, lane = t & 63;
    const int l15 = lane & 15, q4 = lane >> 4;

    const size_t base  = (size_t)bh * SEQ * DHD;   // q/k head-major
    const size_t vbase = (size_t)bh * DHD * SEQ;   // vT

    const int q0 = qt * 128 + wave * 32;

    // staging lane constants: wave stages rows [wave*16, wave*16+16)
    const int sr0 = wave * 16 + (lane >> 3);            // rows sr0 and sr0+8
    const int cg  = ((lane & 7) ^ (sr0 & 7)) * 8;       // swizzled src col (u16)
    const u16* gK = &k_ws [base  + (size_t)sr0 * DHD + cg];
    const u16* gV = &vT_ws[vbase + (size_t)sr0 * SEQ + cg];
    const int ldst = sr0 * 64 + (lane & 7) * 8;         // linear LDS dest (u16)

    u16x8 ou;
#pragma unroll
    for (int j = 0; j < 8; ++j) ou[j] = 0x3F80;
    const bf16x8 ones = __builtin_bit_cast(bf16x8, ou);

    bf16x8 qf[2][2];
#pragma unroll
    for (int mi = 0; mi < 2; ++mi)
#pragma unroll
        for (int c = 0; c < 2; ++c)
            qf[mi][c] = *(const bf16x8*)&q_ws[base + (size_t)(q0 + mi * 16 + l15) * DHD + c * 32 + q4 * 8];

    f32x4 o4[2][4] = {};
    f32x4 l_acc[2] = {};

    const int swz  = (l15 & 7) * 8;      // read-side XOR for K/V (u16 units)

    // prologue: stage K tile 0 into buffer 0
    gld16(gK,       &Kbuf[0][ldst]);
    gld16(gK + 512, &Kbuf[0][ldst + 512]);

    int cur = 0;
    for (int kt = 0; kt < kt_n; ++kt) {
        __syncthreads();   // implicit vmcnt(0): own K[kt] DMA done; all waves
                           // arrived => K[kt] fully in LDS, V[kt-1] consumed.
        // issue V[kt] into the single V buffer (latency hides under QK+softmax)
        {
            const u16* vv = gV + (size_t)kt * 64;
            gld16(vv,                   &Vbuf[ldst]);
            gld16(vv + (size_t)8 * SEQ, &Vbuf[ldst + 512]);
        }
        const bool pre = (kt + 1 < kt_n);
        if (pre) {
            const u16* kk = gK + (size_t)(kt + 1) * 64 * DHD;
            int bf = cur ^ 1;
            gld16(kk,       &Kbuf[bf][ldst]);
            gld16(kk + 512, &Kbuf[bf][ldst + 512]);
        }

        const u16* KK = Kbuf[cur];

        // swapped QK^T: s4[mi][ni][r] = S[q = mi*16+l15][key = ni*16+q4*4+r]
        f32x4 s4[2][4] = {};
#pragma unroll
        for (int c = 0; c < 2; ++c)
#pragma unroll
            for (int ni = 0; ni < 4; ++ni) {
                bf16x8 kf = *(const bf16x8*)&KK[(ni * 16 + l15) * 64 + ((c * 32 + q4 * 8) ^ swz)];
#pragma unroll
                for (int mi = 0; mi < 2; ++mi)
                    s4[mi][ni] = __builtin_amdgcn_mfma_f32_16x16x32_bf16(kf, qf[mi][c], s4[mi][ni], 0, 0, 0);
            }

        // softmax -> Ps (col XOR-swizzled by (qrow&7)*8; b64 stores stay in-group)
        const bool tile_full = valid0 || (kt * 64 + 64 <= valid_eff);
        if (tile_full) {
#pragma unroll
            for (int mi = 0; mi < 2; ++mi) {
                int qrow = mi * 16 + l15;
                int psw  = (l15 & 7) * 8;
#pragma unroll
                for (int ni = 0; ni < 4; ++ni) {
                    u16x4 pk;
#pragma unroll
                    for (int r = 0; r < 4; ++r) {
                        float p = __builtin_amdgcn_exp2f(__builtin_fmaf(s4[mi][ni][r], c2, -M2));
                        pk[r] = bfbits(p);
                    }
                    *(u16x4*)&Ps[wave][qrow][(ni * 16 + q4 * 4) ^ psw] = pk;
                }
            }
        } else {
#pragma unroll
            for (int mi = 0; mi < 2; ++mi) {
                int qrow = mi * 16 + l15;
                int psw  = (l15 & 7) * 8;
#pragma unroll
                for (int ni = 0; ni < 4; ++ni) {
                    u16x4 pk;
#pragma unroll
                    for (int r = 0; r < 4; ++r) {
                        bool ok = (kt * 64 + ni * 16 + q4 * 4 + r) < valid_eff;
                        float arg = ok ? __builtin_fmaf(s4[mi][ni][r], c2, -M2) : -1e30f;
                        pk[r] = bfbits(__builtin_amdgcn_exp2f(arg));
                    }
                    *(u16x4*)&Ps[wave][qrow][(ni * 16 + q4 * 4) ^ psw] = pk;
                }
            }
        }

        // mid-tile barrier: drain V[kt] (2 oldest loads) but keep K[kt+1] in
        // flight across the barrier (counted vmcnt, T4).
        if (pre) asm volatile("s_waitcnt vmcnt(2)\n\ts_barrier" ::: "memory");
        else     asm volatile("s_waitcnt vmcnt(0)\n\ts_barrier" ::: "memory");

        // O += P @ V ;  l += P @ 1
#pragma unroll
        for (int c = 0; c < 2; ++c) {
            bf16x8 pf[2];
#pragma unroll
            for (int mi = 0; mi < 2; ++mi) {
                pf[mi] = *(const bf16x8*)&Ps[wave][mi * 16 + l15][(c * 32 + q4 * 8) ^ ((l15 & 7) * 8)];
                l_acc[mi] = __builtin_amdgcn_mfma_f32_16x16x32_bf16(pf[mi], ones, l_acc[mi], 0, 0, 0);
            }
#pragma unroll
            for (int dt = 0; dt < 4; ++dt) {
                bf16x8 vf = *(const bf16x8*)&Vbuf[(dt * 16 + l15) * 64 + ((c * 32 + q4 * 8) ^ swz)];
#pragma unroll
                for (int mi = 0; mi < 2; ++mi)
                    o4[mi][dt] = __builtin_amdgcn_mfma_f32_16x16x32_bf16(pf[mi], vf, o4[mi][dt], 0, 0, 0);
            }
        }
        cur ^= 1;
    }

    // epilogue: concat heads -> o_ws[(b*S+q)*D + h*64+dh]  (bf16)
#pragma unroll
    for (int mi = 0; mi < 2; ++mi) {
        float inv[4];
#pragma unroll
        for (int r = 0; r < 4; ++r) inv[r] = 1.0f / l_acc[mi][r];
        int qrow = q0 + mi * 16 + q4 * 4;
#pragma unroll
        for (int dt = 0; dt < 4; ++dt) {
            int dh = dt * 16 + l15;
#pragma unroll
            for (int r = 0; r < 4; ++r) {
                float v = o4[mi][dt][r] * inv[r];
                o_ws[((size_t)(b * SEQ + qrow + r) << 10) | (h * DHD + dh)] = bfbits(v);
            }
        }
    }
}

// ---------------------------------------------------------------------------
extern "C" void kernel_launch(void* const* d_in, const int* in_sizes, int n_in,
                              void* d_out, int out_size, void* d_ws, size_t ws_size,
                              hipStream_t stream)
{
    (void)in_sizes; (void)n_in; (void)out_size;
    const float* Q  = (const float*)d_in[0];
    const float* Kb = (const float*)d_in[1];
    const float* V  = (const float*)d_in[2];
    const int*   vl = (const int*)d_in[3];
    const float* Wq = (const float*)d_in[4];
    const float* Wk = (const float*)d_in[5];
    const float* Wv = (const float*)d_in[6];
    const float* Wo = (const float*)d_in[7];
    float* out = (float*)d_out;

    char* ws = (char*)d_ws;
    u16* WqT   = (u16*)(ws + (size_t)0);
    u16* WkT   = (u16*)(ws + ((size_t)2 << 20));
    u16* WvT   = (u16*)(ws + ((size_t)4 << 20));
    u16* WoT   = (u16*)(ws + ((size_t)6 << 20));
    u16* q_ws  = (u16*)(ws + ((size_t)8 << 20));
    u16* k_ws  = (u16*)(ws + ((size_t)24 << 20));
    u16* vT_ws = (u16*)(ws + ((size_t)40 << 20));
    u16* o_ws  = (u16*)(ws + ((size_t)56 << 20));   // attn out / serial A-scratch
    u16* Qbf   = (u16*)(ws + ((size_t)72 << 20));   // fused-path scratch
    u16* Kbf   = (u16*)(ws + ((size_t)88 << 20));
    u16* Vbf   = (u16*)(ws + ((size_t)104 << 20));

    transpose4<<<dim3(32, 32, 4), dim3(32, 8), 0, stream>>>(
        Wq, Wk, Wv, Wo, WqT, WkT, WvT, WoT);

    const bool fused = ws_size >= ((size_t)120 << 20);
    if (fused) {
        cvt3<<<dim3(4096, 1, 3), 256, 0, stream>>>(Q, Kb, V, Qbf, Kbf, Vbf, vl);
        gemm_bt16<3><<<dim3(8, 64, 3), 256, 0, stream>>>(
            Qbf, Kbf, Vbf, WqT, WkT, WvT, q_ws, k_ws, vT_ws, vl);
    } else {
        cvt1<<<4096, 256, 0, stream>>>(Q, o_ws);
        gemm_bt16<0><<<dim3(8, 64), 256, 0, stream>>>(
            o_ws, nullptr, nullptr, WqT, nullptr, nullptr, q_ws, nullptr, nullptr, nullptr);
        cvt1<<<4096, 256, 0, stream>>>(Kb, o_ws);
        gemm_bt16<0><<<dim3(8, 64), 256, 0, stream>>>(
            o_ws, nullptr, nullptr, WkT, nullptr, nullptr, k_ws, nullptr, nullptr, nullptr);
        cvt1<<<4096, 256, 0, stream>>>(V, o_ws);
        gemm_bt16<2><<<dim3(8, 64), 256, 0, stream>>>(
            o_ws, nullptr, nullptr, WvT, nullptr, nullptr, vT_ws, nullptr, nullptr, nullptr);
    }

    attn<<<dim3(16, 64), 256, 0, stream>>>(q_ws, k_ws, vT_ws, vl, o_ws);

    gemm_bt16<1><<<dim3(8, 64), 256, 0, stream>>>(
        o_ws, nullptr, nullptr, WoT, nullptr, nullptr, out, nullptr, nullptr, nullptr);
}

// Round 7
// 279.519 us; speedup vs baseline: 1.1543x; 1.0369x over previous
//
#include <hip/hip_runtime.h>
#include <stdint.h>

typedef unsigned short u16;
using bf16x8 = __attribute__((ext_vector_type(8))) __bf16;
using f32x4  = __attribute__((ext_vector_type(4))) float;
using u16x8  = __attribute__((ext_vector_type(8))) unsigned short;
using u16x4  = __attribute__((ext_vector_type(4))) unsigned short;

#define NH   16
#define DHD  64
#define SEQ  2048
#define DD   1024

__device__ inline u16 bfbits(float f) {
    __bf16 h = (__bf16)f;                 // RTNE
    return __builtin_bit_cast(u16, h);
}

// async global->LDS, 16 B per lane (global_load_lds_dwordx4)
__device__ inline void gld16(const u16* g, u16* l) {
    __builtin_amdgcn_global_load_lds(
        (const __attribute__((address_space(1))) void*)g,
        (__attribute__((address_space(3))) void*)l,
        16, 0, 0);
}

// ---------------------------------------------------------------------------
// Transpose+convert 4 weight matrices (1024x1024): Wt_bf16[n][k] = W_f32[k][n]
// ---------------------------------------------------------------------------
__global__ __launch_bounds__(256) void transpose4(
    const float* __restrict__ s0, const float* __restrict__ s1,
    const float* __restrict__ s2, const float* __restrict__ s3,
    u16* __restrict__ d0, u16* __restrict__ d1,
    u16* __restrict__ d2, u16* __restrict__ d3)
{
    const float* src = s0; u16* dst = d0;
    if (blockIdx.z == 1) { src = s1; dst = d1; }
    else if (blockIdx.z == 2) { src = s2; dst = d2; }
    else if (blockIdx.z == 3) { src = s3; dst = d3; }

    __shared__ u16 tile[32][33];
    int tx = threadIdx.x, ty = threadIdx.y;            // block (32,8)
    int x = blockIdx.x * 32 + tx;
    int y0 = blockIdx.y * 32 + ty;
#pragma unroll
    for (int i = 0; i < 32; i += 8)
        tile[ty + i][tx] = bfbits(src[(size_t)(y0 + i) * DD + x]);
    __syncthreads();
    int x2 = blockIdx.y * 32 + tx;
    int y2 = blockIdx.x * 32 + ty;
#pragma unroll
    for (int i = 0; i < 32; i += 8)
        dst[(size_t)(y2 + i) * DD + x2] = tile[tx][ty + i];
}

// ---------------------------------------------------------------------------
// Streaming f32 -> bf16 convert (8 elements/thread). cvt3: three matrices.
// For z>=1 (K,V inputs): rows entirely beyond the per-batch validity limit
// (rounded up to the GEMM's 128-row tile) are never read by the projection
// GEMM (those tiles early-exit) -> skip the conversion (block-uniform).
// ---------------------------------------------------------------------------
__global__ __launch_bounds__(256) void cvt3(
    const float* __restrict__ s0, const float* __restrict__ s1,
    const float* __restrict__ s2,
    u16* __restrict__ d0, u16* __restrict__ d1, u16* __restrict__ d2,
    const int* __restrict__ vl)
{
    const float* src = s0; u16* dst = d0;
    if (blockIdx.z == 1) { src = s1; dst = d1; }
    else if (blockIdx.z == 2) { src = s2; dst = d2; }

    if (blockIdx.z != 0) {
        int r = blockIdx.x * 2;            // first of 2 rows this block covers
        int v = vl[r >> 11];
        int ve = (v == 0) ? SEQ : v;
        int lim = ((ve + 127) >> 7) << 7;  // GEMM read extent (tile-rounded)
        if ((r & (SEQ - 1)) >= lim) return;
    }

    size_t i = ((size_t)blockIdx.x * 256 + threadIdx.x) * 8;
    f32x4 a = *(const f32x4*)&src[i];
    f32x4 b = *(const f32x4*)&src[i + 4];
    u16x8 o;
#pragma unroll
    for (int j = 0; j < 4; ++j) { o[j] = bfbits(a[j]); o[j + 4] = bfbits(b[j]); }
    *(u16x8*)&dst[i] = o;
}

__global__ __launch_bounds__(256) void cvt1(
    const float* __restrict__ src, u16* __restrict__ dst)
{
    size_t i = ((size_t)blockIdx.x * 256 + threadIdx.x) * 8;
    f32x4 a = *(const f32x4*)&src[i];
    f32x4 b = *(const f32x4*)&src[i + 4];
    u16x8 o;
#pragma unroll
    for (int j = 0; j < 4; ++j) { o[j] = bfbits(a[j]); o[j + 4] = bfbits(b[j]); }
    *(u16x8*)&dst[i] = o;
}

// ---------------------------------------------------------------------------
// GEMM: C(8192 x 1024) = A(8192 x 1024 bf16) @ B, B given transposed (Bt: N x K).
// 128x128 tile, BK=64, TILE-LEVEL LDS DOUBLE-BUFFER: one __syncthreads per
// K-step; the barrier's compiler-emitted vmcnt(0) drains the PREVIOUS
// iteration's prefetch (issued a full compute phase earlier -> latency
// hidden). Layout [128][64] u16 with XOR bank-swizzle (pre-swizzled global
// source + XOR'd read; same pattern as attn) -> conflict-free b128 reads.
// 4 waves (2x2), wave 64x64. XCD-chunked bijective block swizzle.
// MODE 0: bf16 head-major (b,h,s,dh)
// MODE 2: bf16 transposed head-major [(bh*64+dh)*2048+s] (packed b64 stores)
// MODE 1: f32 row-major
// MODE 3: fused QKV via blockIdx.z; z>=1 K/V tiles past valid_eff early-exit.
// ---------------------------------------------------------------------------
template<int MODE>
__global__ __launch_bounds__(256) void gemm_bt16(
    const u16* __restrict__ A0, const u16* __restrict__ A1, const u16* __restrict__ A2,
    const u16* __restrict__ B0, const u16* __restrict__ B1, const u16* __restrict__ B2,
    void* __restrict__ C0, void* __restrict__ C1, void* __restrict__ C2,
    const int* __restrict__ vl)
{
    const int K = 1024;
    const u16* A = A0; const u16* Bt = B0; void* C = C0;
    if (MODE == 3) {
        if (blockIdx.z == 1) { A = A1; Bt = B1; C = C1; }
        else if (blockIdx.z == 2) { A = A2; Bt = B2; C = C2; }
    }

    __shared__ __align__(16) u16 As[2][128 * 64];
    __shared__ __align__(16) u16 Bs[2][128 * 64];

    const int t = threadIdx.x;
    const int wave = t >> 6, lane = t & 63;
    const int l15 = lane & 15, q4 = lane >> 4;
    const int wm = (wave >> 1) * 64, wn = (wave & 1) * 64;

    // XCD-chunked bijective swizzle (nwg % 8 == 0)
    const int gx = gridDim.x;
    const int nwg = gx * gridDim.y;
    int flat = blockIdx.y * gx + blockIdx.x;
    flat = (flat & 7) * (nwg >> 3) + (flat >> 3);
    const int m0 = (flat / gx) * 128, n0 = (flat % gx) * 128;

    if (MODE == 3 && blockIdx.z != 0) {
        int v = vl[m0 >> 11];
        int ve = (v == 0) ? SEQ : v;
        if ((m0 & (SEQ - 1)) >= ve) return;   // block-uniform, pre-barrier
    }

    // staging lane constants: thread covers rows {sr, sr+32, sr+64, sr+96}
    const int sr = t >> 3;                  // 0..31
    const int sg = (t & 7) ^ (sr & 7);      // pre-swizzled source col-group
    const u16* gA = &A [(size_t)(m0 + sr) * K + sg * 8];
    const u16* gB = &Bt[(size_t)(n0 + sr) * K + sg * 8];

    const int xr = (l15 & 7) * 8;           // read-side XOR (u16 units)

    f32x4 acc[4][4] = {};

    // prologue: stage tile k0=0 into buffer 0
#pragma unroll
    for (int is = 0; is < 4; ++is) {
        gld16(gA + (size_t)(is * 32) * K, &As[0][is * 2048 + t * 8]);
        gld16(gB + (size_t)(is * 32) * K, &Bs[0][is * 2048 + t * 8]);
    }

    int cur = 0;
    for (int k0 = 0; k0 < K; k0 += 64) {
        __syncthreads();   // vmcnt(0) drain (own prefetch) + barrier:
                           // buf[cur] fully in LDS; prev compute done everywhere.
        if (k0 + 64 < K) {
            const int nb = cur ^ 1;
            const size_t ko = k0 + 64;
#pragma unroll
            for (int is = 0; is < 4; ++is) {
                gld16(gA + (size_t)(is * 32) * K + ko, &As[nb][is * 2048 + t * 8]);
                gld16(gB + (size_t)(is * 32) * K + ko, &Bs[nb][is * 2048 + t * 8]);
            }
        }

#pragma unroll
        for (int hf = 0; hf < 2; ++hf) {
            bf16x8 af[4], bfr[4];
#pragma unroll
            for (int i = 0; i < 4; ++i) {
                af[i]  = *(const bf16x8*)&As[cur][(wm + i * 16 + l15) * 64 + ((hf * 32 + q4 * 8) ^ xr)];
                bfr[i] = *(const bf16x8*)&Bs[cur][(wn + i * 16 + l15) * 64 + ((hf * 32 + q4 * 8) ^ xr)];
            }
#pragma unroll
            for (int i = 0; i < 4; ++i)
#pragma unroll
                for (int j = 0; j < 4; ++j)
                    acc[i][j] = __builtin_amdgcn_mfma_f32_16x16x32_bf16(af[i], bfr[j], acc[i][j], 0, 0, 0);
        }
        cur ^= 1;
    }

    const bool vt_store = (MODE == 2) || (MODE == 3 && blockIdx.z == 2);

    // epilogue: D layout col=lane&15, row=(lane>>4)*4+reg
#pragma unroll
    for (int i = 0; i < 4; ++i) {
        int row_l = wm + i * 16 + q4 * 4;
#pragma unroll
        for (int j = 0; j < 4; ++j) {
            int col = n0 + wn + j * 16 + l15;
            if (MODE == 1) {
#pragma unroll
                for (int r = 0; r < 4; ++r) {
                    int row = m0 + row_l + r;
                    ((float*)C)[(size_t)row * DD + col] = acc[i][j][r];
                }
            } else if (vt_store) {
                int row = m0 + row_l;
                int b = row >> 11, s = row & (SEQ - 1);
                int h = col >> 6, dh = col & (DHD - 1);
                u16x4 pk;
#pragma unroll
                for (int r = 0; r < 4; ++r) pk[r] = bfbits(acc[i][j][r]);
                *(u16x4*)&((u16*)C)[(((size_t)(b * NH + h) * DHD + dh) << 11) | s] = pk;
            } else {
#pragma unroll
                for (int r = 0; r < 4; ++r) {
                    int row = m0 + row_l + r;
                    int b = row >> 11, s = row & (SEQ - 1);
                    int h = col >> 6, dh = col & (DHD - 1);
                    ((u16*)C)[(((size_t)(b * NH + h) * SEQ + s) << 6) | dh] = bfbits(acc[i][j][r]);
                }
            }
        }
    }
}

// ---------------------------------------------------------------------------
// Flash attention: one block per (b,h, 128-row q-tile). 4 waves, 32 q-rows each.
// q/k head-major (b,h,s,dh); v transposed head-major (b,h,dh,s). All bf16.
// Fixed-max softmax: p = exp2(s*c2 - M2) via raw v_exp_f32; masked -> 0 exact.
// K-tiles fully beyond valid are SKIPPED (exact). valid==0 -> uniform weights.
// Swapped QK^T (mfma(kf,qf)): packed u16x4 P stores; no shuffles anywhere.
// Staging: K double-buffered + V SINGLE-buffered via global_load_lds with XOR
// bank-swizzle (pre-swizzled global source + XOR'd read). Per tile:
//   syncthreads -> issue V[t] DMA, issue K[t+1] DMA -> QK^T -> softmax -> Ps
//   -> s_waitcnt vmcnt(2) + s_barrier (V[t] drained, K[t+1] stays in flight)
//   -> PV. LDS = 40960 B -> 4 blocks/CU.
// ---------------------------------------------------------------------------
__global__ __launch_bounds__(256, 4) void attn(
    const u16* __restrict__ q_ws, const u16* __restrict__ k_ws,
    const u16* __restrict__ vT_ws, const int* __restrict__ valid_lens,
    u16* __restrict__ o_ws)
{
    const int bh = blockIdx.y;           // 0..63
    const int b = bh >> 4, h = bh & 15;
    const int qt = blockIdx.x;           // 0..15
    const int valid = valid_lens[b];
    const bool valid0 = (valid == 0);
    const int valid_eff = valid0 ? SEQ : valid;
    const int kt_n = (valid_eff + 63) >> 6;
    const float c2 = valid0 ? 0.f : 0.18033688011112042f;   // 0.125*log2(e)
    const float M2 = 17.312340490667562f;                   // 12*log2(e)

    __shared__ __align__(16) u16 Kbuf[2][64 * 64];   // 16 KB (dbuf)
    __shared__ __align__(16) u16 Vbuf[64 * 64];      //  8 KB (single)
    __shared__ __align__(16) u16 Ps[4][32][64];      // 16 KB, XOR-swizzled cols

    const int t = threadIdx.x;
    const int wave = t >> 6, lane = t & 63;
    const int l15 = lane & 15, q4 = lane >> 4;

    const size_t base  = (size_t)bh * SEQ * DHD;   // q/k head-major
    const size_t vbase = (size_t)bh * DHD * SEQ;   // vT

    const int q0 = qt * 128 + wave * 32;

    // staging lane constants: wave stages rows [wave*16, wave*16+16)
    const int sr0 = wave * 16 + (lane >> 3);            // rows sr0 and sr0+8
    const int cg  = ((lane & 7) ^ (sr0 & 7)) * 8;       // swizzled src col (u16)
    const u16* gK = &k_ws [base  + (size_t)sr0 * DHD + cg];
    const u16* gV = &vT_ws[vbase + (size_t)sr0 * SEQ + cg];
    const int ldst = sr0 * 64 + (lane & 7) * 8;         // linear LDS dest (u16)

    u16x8 ou;
#pragma unroll
    for (int j = 0; j < 8; ++j) ou[j] = 0x3F80;
    const bf16x8 ones = __builtin_bit_cast(bf16x8, ou);

    bf16x8 qf[2][2];
#pragma unroll
    for (int mi = 0; mi < 2; ++mi)
#pragma unroll
        for (int c = 0; c < 2; ++c)
            qf[mi][c] = *(const bf16x8*)&q_ws[base + (size_t)(q0 + mi * 16 + l15) * DHD + c * 32 + q4 * 8];

    f32x4 o4[2][4] = {};
    f32x4 l_acc[2] = {};

    const int swz  = (l15 & 7) * 8;      // read-side XOR for K/V (u16 units)

    // prologue: stage K tile 0 into buffer 0
    gld16(gK,       &Kbuf[0][ldst]);
    gld16(gK + 512, &Kbuf[0][ldst + 512]);

    int cur = 0;
    for (int kt = 0; kt < kt_n; ++kt) {
        __syncthreads();   // implicit vmcnt(0): own K[kt] DMA done; all waves
                           // arrived => K[kt] fully in LDS, V[kt-1] consumed.
        // issue V[kt] into the single V buffer (latency hides under QK+softmax)
        {
            const u16* vv = gV + (size_t)kt * 64;
            gld16(vv,                   &Vbuf[ldst]);
            gld16(vv + (size_t)8 * SEQ, &Vbuf[ldst + 512]);
        }
        const bool pre = (kt + 1 < kt_n);
        if (pre) {
            const u16* kk = gK + (size_t)(kt + 1) * 64 * DHD;
            int bf = cur ^ 1;
            gld16(kk,       &Kbuf[bf][ldst]);
            gld16(kk + 512, &Kbuf[bf][ldst + 512]);
        }

        const u16* KK = Kbuf[cur];

        // swapped QK^T: s4[mi][ni][r] = S[q = mi*16+l15][key = ni*16+q4*4+r]
        f32x4 s4[2][4] = {};
#pragma unroll
        for (int c = 0; c < 2; ++c)
#pragma unroll
            for (int ni = 0; ni < 4; ++ni) {
                bf16x8 kf = *(const bf16x8*)&KK[(ni * 16 + l15) * 64 + ((c * 32 + q4 * 8) ^ swz)];
#pragma unroll
                for (int mi = 0; mi < 2; ++mi)
                    s4[mi][ni] = __builtin_amdgcn_mfma_f32_16x16x32_bf16(kf, qf[mi][c], s4[mi][ni], 0, 0, 0);
            }

        // softmax -> Ps (col XOR-swizzled by (qrow&7)*8; b64 stores stay in-group)
        const bool tile_full = valid0 || (kt * 64 + 64 <= valid_eff);
        if (tile_full) {
#pragma unroll
            for (int mi = 0; mi < 2; ++mi) {
                int qrow = mi * 16 + l15;
                int psw  = (l15 & 7) * 8;
#pragma unroll
                for (int ni = 0; ni < 4; ++ni) {
                    u16x4 pk;
#pragma unroll
                    for (int r = 0; r < 4; ++r) {
                        float p = __builtin_amdgcn_exp2f(__builtin_fmaf(s4[mi][ni][r], c2, -M2));
                        pk[r] = bfbits(p);
                    }
                    *(u16x4*)&Ps[wave][qrow][(ni * 16 + q4 * 4) ^ psw] = pk;
                }
            }
        } else {
#pragma unroll
            for (int mi = 0; mi < 2; ++mi) {
                int qrow = mi * 16 + l15;
                int psw  = (l15 & 7) * 8;
#pragma unroll
                for (int ni = 0; ni < 4; ++ni) {
                    u16x4 pk;
#pragma unroll
                    for (int r = 0; r < 4; ++r) {
                        bool ok = (kt * 64 + ni * 16 + q4 * 4 + r) < valid_eff;
                        float arg = ok ? __builtin_fmaf(s4[mi][ni][r], c2, -M2) : -1e30f;
                        pk[r] = bfbits(__builtin_amdgcn_exp2f(arg));
                    }
                    *(u16x4*)&Ps[wave][qrow][(ni * 16 + q4 * 4) ^ psw] = pk;
                }
            }
        }

        // mid-tile barrier: drain V[kt] (2 oldest loads) but keep K[kt+1] in
        // flight across the barrier (counted vmcnt, T4).
        if (pre) asm volatile("s_waitcnt vmcnt(2)\n\ts_barrier" ::: "memory");
        else     asm volatile("s_waitcnt vmcnt(0)\n\ts_barrier" ::: "memory");

        // O += P @ V ;  l += P @ 1
#pragma unroll
        for (int c = 0; c < 2; ++c) {
            bf16x8 pf[2];
#pragma unroll
            for (int mi = 0; mi < 2; ++mi) {
                pf[mi] = *(const bf16x8*)&Ps[wave][mi * 16 + l15][(c * 32 + q4 * 8) ^ ((l15 & 7) * 8)];
                l_acc[mi] = __builtin_amdgcn_mfma_f32_16x16x32_bf16(pf[mi], ones, l_acc[mi], 0, 0, 0);
            }
#pragma unroll
            for (int dt = 0; dt < 4; ++dt) {
                bf16x8 vf = *(const bf16x8*)&Vbuf[(dt * 16 + l15) * 64 + ((c * 32 + q4 * 8) ^ swz)];
#pragma unroll
                for (int mi = 0; mi < 2; ++mi)
                    o4[mi][dt] = __builtin_amdgcn_mfma_f32_16x16x32_bf16(pf[mi], vf, o4[mi][dt], 0, 0, 0);
            }
        }
        cur ^= 1;
    }

    // epilogue: concat heads -> o_ws[(b*S+q)*D + h*64+dh]  (bf16)
#pragma unroll
    for (int mi = 0; mi < 2; ++mi) {
        float inv[4];
#pragma unroll
        for (int r = 0; r < 4; ++r) inv[r] = 1.0f / l_acc[mi][r];
        int qrow = q0 + mi * 16 + q4 * 4;
#pragma unroll
        for (int dt = 0; dt < 4; ++dt) {
            int dh = dt * 16 + l15;
#pragma unroll
            for (int r = 0; r < 4; ++r) {
                float v = o4[mi][dt][r] * inv[r];
                o_ws[((size_t)(b * SEQ + qrow + r) << 10) | (h * DHD + dh)] = bfbits(v);
            }
        }
    }
}

// ---------------------------------------------------------------------------
extern "C" void kernel_launch(void* const* d_in, const int* in_sizes, int n_in,
                              void* d_out, int out_size, void* d_ws, size_t ws_size,
                              hipStream_t stream)
{
    (void)in_sizes; (void)n_in; (void)out_size;
    const float* Q  = (const float*)d_in[0];
    const float* Kb = (const float*)d_in[1];
    const float* V  = (const float*)d_in[2];
    const int*   vl = (const int*)d_in[3];
    const float* Wq = (const float*)d_in[4];
    const float* Wk = (const float*)d_in[5];
    const float* Wv = (const float*)d_in[6];
    const float* Wo = (const float*)d_in[7];
    float* out = (float*)d_out;

    char* ws = (char*)d_ws;
    u16* WqT   = (u16*)(ws + (size_t)0);
    u16* WkT   = (u16*)(ws + ((size_t)2 << 20));
    u16* WvT   = (u16*)(ws + ((size_t)4 << 20));
    u16* WoT   = (u16*)(ws + ((size_t)6 << 20));
    u16* q_ws  = (u16*)(ws + ((size_t)8 << 20));
    u16* k_ws  = (u16*)(ws + ((size_t)24 << 20));
    u16* vT_ws = (u16*)(ws + ((size_t)40 << 20));
    u16* o_ws  = (u16*)(ws + ((size_t)56 << 20));   // attn out / serial A-scratch
    u16* Qbf   = (u16*)(ws + ((size_t)72 << 20));   // fused-path scratch
    u16* Kbf   = (u16*)(ws + ((size_t)88 << 20));
    u16* Vbf   = (u16*)(ws + ((size_t)104 << 20));

    transpose4<<<dim3(32, 32, 4), dim3(32, 8), 0, stream>>>(
        Wq, Wk, Wv, Wo, WqT, WkT, WvT, WoT);

    const bool fused = ws_size >= ((size_t)120 << 20);
    if (fused) {
        cvt3<<<dim3(4096, 1, 3), 256, 0, stream>>>(Q, Kb, V, Qbf, Kbf, Vbf, vl);
        gemm_bt16<3><<<dim3(8, 64, 3), 256, 0, stream>>>(
            Qbf, Kbf, Vbf, WqT, WkT, WvT, q_ws, k_ws, vT_ws, vl);
    } else {
        cvt1<<<4096, 256, 0, stream>>>(Q, o_ws);
        gemm_bt16<0><<<dim3(8, 64), 256, 0, stream>>>(
            o_ws, nullptr, nullptr, WqT, nullptr, nullptr, q_ws, nullptr, nullptr, nullptr);
        cvt1<<<4096, 256, 0, stream>>>(Kb, o_ws);
        gemm_bt16<0><<<dim3(8, 64), 256, 0, stream>>>(
            o_ws, nullptr, nullptr, WkT, nullptr, nullptr, k_ws, nullptr, nullptr, nullptr);
        cvt1<<<4096, 256, 0, stream>>>(V, o_ws);
        gemm_bt16<2><<<dim3(8, 64), 256, 0, stream>>>(
            o_ws, nullptr, nullptr, WvT, nullptr, nullptr, vT_ws, nullptr, nullptr, nullptr);
    }

    attn<<<dim3(16, 64), 256, 0, stream>>>(q_ws, k_ws, vT_ws, vl, o_ws);

    gemm_bt16<1><<<dim3(8, 64), 256, 0, stream>>>(
        o_ws, nullptr, nullptr, WoT, nullptr, nullptr, out, nullptr, nullptr, nullptr);
}